// Round 6
// baseline (263.069 us; speedup 1.0000x reference)
//
#include <hip/hip_runtime.h>
#include <hip/hip_fp16.h>

#define NNODES 50000
#define NEDGES 800000
#define NBUCK 49        // dst>>10 buckets (1024 nodes each)
#define NSLICE 16
#define SLICE_E 50000   // NEDGES / NSLICE
#define CHUNK_E 3125    // SLICE_E / 16

typedef _Float16 f16x8 __attribute__((ext_vector_type(8)));
typedef float f32x4 __attribute__((ext_vector_type(4)));

// ============================= CSR build (bucket sort) =====================
// Edge packs into u32: (dst<<16)|src  (both < 65536). bucket = dst>>10 = v>>26.

__global__ __launch_bounds__(256) void k_packhist(const int* __restrict__ src,
                                                  const int* __restrict__ dst,
                                                  unsigned* __restrict__ pack,
                                                  int* __restrict__ hist2) {
  __shared__ int h[NBUCK];
  int t = threadIdx.x, j = blockIdx.x;
  int s = j >> 4, c = j & 15;
  if (t < NBUCK) h[t] = 0;
  __syncthreads();
  int beg = s * SLICE_E + c * CHUNK_E;
  for (int q = t; q < CHUNK_E; q += 256) {
    int e = beg + q;
    unsigned d = (unsigned)dst[e], sv = (unsigned)src[e];
    pack[e] = (d << 16) | sv;
    atomicAdd(&h[d >> 10], 1);
  }
  __syncthreads();
  if (t < NBUCK) atomicAdd(&hist2[t * NSLICE + s], h[t]);
}

// exclusive scan of hist2[NBUCK*NSLICE] (bucket-major) -> off2
__global__ __launch_bounds__(1024) void k_scan784(const int* __restrict__ hist2,
                                                  int* __restrict__ off2) {
  __shared__ int sb[1024];
  int t = threadIdx.x;
  int v = (t < NBUCK * NSLICE) ? hist2[t] : 0;
  sb[t] = v;
  __syncthreads();
  for (int off = 1; off < 1024; off <<= 1) {
    int x = (t >= off) ? sb[t - off] : 0;
    __syncthreads();
    sb[t] += x;
    __syncthreads();
  }
  if (t < NBUCK * NSLICE) off2[t] = sb[t] - v;  // exclusive
}

// block (b,s): stream slice s of pack[], compact bucket-b edges to bucketed[]
__global__ __launch_bounds__(1024) void k_compact(const unsigned* __restrict__ pack,
                                                  const int* __restrict__ off2,
                                                  unsigned* __restrict__ bucketed) {
  __shared__ int lw[16];
  int t = threadIdx.x, j = blockIdx.x;
  int b = j >> 4, s = j & 15;
  int wbase = off2[b * NSLICE + s];
  int beg = s * SLICE_E, end = beg + SLICE_E;
  int wid = t >> 6, lane = t & 63;
  for (int i0 = beg; i0 < end; i0 += 1024) {
    int i = i0 + t;
    unsigned v = 0;
    bool match = false;
    if (i < end) {
      v = pack[i];
      match = ((int)(v >> 26) == b);
    }
    unsigned long long mb = __ballot(match);
    if (lane == 0) lw[wid] = __popcll(mb);
    __syncthreads();
    int wex = 0, tot = 0;
    #pragma unroll
    for (int k = 0; k < 16; ++k) {
      int cc = lw[k];
      if (k < wid) wex += cc;
      tot += cc;
    }
    if (match) {
      int rank = wex + __popcll(mb & ((1ull << lane) - 1ull));
      bucketed[wbase + rank] = v;
    }
    wbase += tot;
    __syncthreads();
  }
}

// one block per bucket: LDS counting sort over the 1024-node range ->
// row_off (global) + esrc (scatter into L2-resident 65KB region).
__global__ __launch_bounds__(1024) void k_sortbkt(const unsigned* __restrict__ bucketed,
                                                  const int* __restrict__ off2,
                                                  int* __restrict__ row_off,
                                                  int* __restrict__ esrc) {
  __shared__ int cnt[1024];
  __shared__ int cur[1024];
  int t = threadIdx.x, b = blockIdx.x;
  int base = off2[b * NSLICE];
  int endb = (b == NBUCK - 1) ? NEDGES : off2[(b + 1) * NSLICE];
  int ne = endb - base;
  cnt[t] = 0;
  __syncthreads();
  for (int i = t; i < ne; i += 1024)
    atomicAdd(&cnt[(bucketed[base + i] >> 16) & 1023], 1);
  __syncthreads();
  int orig = cnt[t];
  cur[t] = orig;
  __syncthreads();
  for (int off = 1; off < 1024; off <<= 1) {
    int x = (t >= off) ? cur[t - off] : 0;
    __syncthreads();
    cur[t] += x;
    __syncthreads();
  }
  int excl = cur[t] - orig;
  int g = (b << 10) + t;
  if (g <= NNODES) row_off[g] = base + excl;
  cur[t] = excl;
  __syncthreads();
  for (int i = t; i < ne; i += 1024) {
    unsigned v = bucketed[base + i];
    int pos = base + atomicAdd(&cur[(v >> 16) & 1023], 1);
    esrc[pos] = (int)(v & 0xFFFFu);
  }
}

// ============================= weight prep =============================
// Wt0/Wt1: [144][128] fp16 = [W^T (128 rows) | W@al head cols (4) | W@ar (4) | zeros (8)]
// Wt2:     [96][128]  fp16 = [W2^T (40) | resW2^T (40) | W2@al2 | W2@ar2 | zeros (14)]
__global__ __launch_bounds__(128) void k_prep(const float* __restrict__ W0, const float* __restrict__ al0,
                                              const float* __restrict__ ar0,
                                              const float* __restrict__ W1, const float* __restrict__ al1,
                                              const float* __restrict__ ar1,
                                              const float* __restrict__ W2, const float* __restrict__ resW2,
                                              const float* __restrict__ al2, const float* __restrict__ ar2,
                                              _Float16* __restrict__ Wt0, _Float16* __restrict__ Wt1,
                                              _Float16* __restrict__ Wt2) {
  int b = blockIdx.x, k = threadIdx.x;
  if (b < 288) {
    const float* W = (b < 144) ? W0 : W1;
    const float* al = (b < 144) ? al0 : al1;
    const float* ar = (b < 144) ? ar0 : ar1;
    _Float16* Wt = (b < 144) ? Wt0 : Wt1;
    int c = (b < 144) ? b : b - 144;
    float v = 0.f;
    if (c < 128) {
      v = W[k * 128 + c];
    } else if (c < 136) {
      int h = c - 128;
      const float* av = (h < 4) ? al : ar;
      int hh = h & 3;
      float s = 0.f;
      for (int d = 0; d < 32; ++d) s += W[k * 128 + hh * 32 + d] * av[hh * 32 + d];
      v = s;
    }
    Wt[c * 128 + k] = (_Float16)v;
  } else {
    int c = b - 288;
    float v = 0.f;
    if (c < 40) {
      v = W2[k * 40 + c];
    } else if (c < 80) {
      v = resW2[k * 40 + (c - 40)];
    } else if (c == 80) {
      float s = 0.f;
      for (int d = 0; d < 40; ++d) s += W2[k * 40 + d] * al2[d];
      v = s;
    } else if (c == 81) {
      float s = 0.f;
      for (int d = 0; d < 40; ++d) s += W2[k * 40 + d] * ar2[d];
      v = s;
    }
    Wt2[c * 128 + k] = (_Float16)v;
  }
}

// ============================= MFMA GEMM =============================
template <int NCT, bool L2E>
__global__ __launch_bounds__(512) void k_gemm_mfma(const float* __restrict__ A,
                                                   const _Float16* __restrict__ Wtg,
                                                   __half* __restrict__ C,
                                                   float* __restrict__ resOut,
                                                   float* __restrict__ el,
                                                   float* __restrict__ er, int nrows) {
  __shared__ _Float16 Ah[128 * 136];
  __shared__ _Float16 Wl[NCT * 16 * 136];
  int t = threadIdx.x;
  int r0 = blockIdx.x * 128;

  for (int q = t; q < NCT * 16 * 16; q += 512) {
    int row = q >> 4, k8 = (q & 15) * 8;
    *(f16x8*)(&Wl[row * 136 + k8]) = *(const f16x8*)(Wtg + row * 128 + k8);
  }
  #pragma unroll
  for (int p = 0; p < 8; ++p) {
    int q = p * 512 + t;
    int r = q >> 5, k4 = (q & 31) * 4;
    float4 v = make_float4(0.f, 0.f, 0.f, 0.f);
    if (r0 + r < nrows) v = *(const float4*)(A + (size_t)(r0 + r) * 128 + k4);
    union { _Float16 h[4]; uint2 u; } pk;
    pk.h[0] = (_Float16)v.x; pk.h[1] = (_Float16)v.y;
    pk.h[2] = (_Float16)v.z; pk.h[3] = (_Float16)v.w;
    *(uint2*)(&Ah[r * 136 + k4]) = pk.u;
  }
  __syncthreads();

  int wave = t >> 6, l = t & 63;
  const _Float16* abase = &Ah[(wave * 16 + (l & 15)) * 136 + ((l >> 4) * 8)];
  const _Float16* bbase = &Wl[(l & 15) * 136 + ((l >> 4) * 8)];

  f32x4 acc[NCT] = {};
  #pragma unroll
  for (int ks = 0; ks < 4; ++ks) {
    f16x8 af = *(const f16x8*)(abase + ks * 32);
    #pragma unroll
    for (int nt = 0; nt < NCT; ++nt) {
      f16x8 bf = *(const f16x8*)(bbase + nt * 16 * 136 + ks * 32);
      acc[nt] = __builtin_amdgcn_mfma_f32_16x16x32_f16(af, bf, acc[nt], 0, 0, 0);
    }
  }

  int cc = l & 15;
  int rbase = r0 + wave * 16 + (l >> 4) * 4;
  #pragma unroll
  for (int r = 0; r < 4; ++r) {
    int row = rbase + r;
    if (row >= nrows) continue;
    if (!L2E) {
      #pragma unroll
      for (int nt = 0; nt < 8; ++nt)
        C[(size_t)row * 128 + nt * 16 + cc] = __float2half_rn(acc[nt][r]);
      float v = acc[8][r];
      if (cc < 4) el[row * 4 + cc] = v;
      else if (cc < 8) er[row * 4 + (cc - 4)] = v;
    } else {
      #pragma unroll
      for (int nt = 0; nt < 6; ++nt) {
        int col = nt * 16 + cc;
        float v = acc[nt][r];
        if (col < 40) C[(size_t)row * 40 + col] = __float2half_rn(v);
        else if (col < 80) resOut[(size_t)row * 40 + (col - 40)] = v;
        else if (col == 80) el[row] = v;
        else if (col == 81) er[row] = v;
      }
    }
  }
}

// ============================= helpers =============================
__device__ __forceinline__ void fma8h(float4& a0, float4& a1, float w, const uint4& r) {
  const __half2* hp = (const __half2*)&r;
  float2 f0 = __half22float2(hp[0]);
  float2 f1 = __half22float2(hp[1]);
  float2 f2 = __half22float2(hp[2]);
  float2 f3 = __half22float2(hp[3]);
  a0.x += w * f0.x; a0.y += w * f0.y; a0.z += w * f1.x; a0.w += w * f1.y;
  a1.x += w * f2.x; a1.y += w * f2.y; a1.z += w * f3.x; a1.w += w * f3.y;
}

// ============================= message passing (fp16 gather) =============
template <bool RES, bool DOELU>
__global__ __launch_bounds__(256) void k_msg128v4(const __half* __restrict__ feat,
                                                  const float* __restrict__ el,
                                                  const float* __restrict__ er,
                                                  const int* __restrict__ row_off,
                                                  const int* __restrict__ esrc,
                                                  const float* __restrict__ hres,
                                                  float* __restrict__ out, int nnodes) {
  int t = threadIdx.x;
  int n = blockIdx.x * 16 + (t >> 4);
  if (n >= nnodes) return;
  int lane = t & 15;          // cols lane*8 .. lane*8+7
  int h = lane >> 2;          // this lane's head
  int s = row_off[n], e = row_off[n + 1];
  float ern = er[n * 4 + h];
  float4 acc0[4] = {}, acc1[4] = {};
  float den[4] = {0.f, 0.f, 0.f, 0.f};

  for (int c = s; c < e; c += 16) {
    int m = e - c; if (m > 16) m = 16;
    int sjv = 0;
    if (lane < m) sjv = esrc[c + lane];
    int e0 = __shfl(sjv, (lane & 3), 16);
    int e1 = __shfl(sjv, (lane & 3) + 4, 16);
    int e2 = __shfl(sjv, (lane & 3) + 8, 16);
    int e3 = __shfl(sjv, (lane & 3) + 12, 16);
    float sel0 = el[e0 * 4 + h];
    float sel1 = el[e1 * 4 + h];
    float sel2 = el[e2 * 4 + h];
    float sel3 = el[e3 * 4 + h];

#define GAT_SUB(KK, SEL)                                                      \
    {                                                                         \
      int b = KK * 4;                                                         \
      if (b < m) {                                                            \
        int mm = m - b; if (mm > 4) mm = 4;                                   \
        _Pragma("unroll")                                                     \
        for (int j = 0; j < 4; ++j) {                                         \
          if (j < mm) {                                                       \
            float ev = __shfl(SEL, (lane & 12) | j, 16);                      \
            float x = ev + ern;                                               \
            x = fmaxf(x, 0.2f * x);                                           \
            float wgt = __expf(x);                                            \
            int sj = __shfl(sjv, b + j, 16);                                  \
            den[j] += wgt;                                                    \
            uint4 raw = *(const uint4*)(feat + (size_t)sj * 128 + lane * 8);  \
            fma8h(acc0[j], acc1[j], wgt, raw);                                \
          }                                                                   \
        }                                                                     \
      }                                                                       \
    }
    GAT_SUB(0, sel0)
    GAT_SUB(1, sel1)
    GAT_SUB(2, sel2)
    GAT_SUB(3, sel3)
#undef GAT_SUB
  }

  float4 A0, A1;
  A0.x = (acc0[0].x + acc0[1].x) + (acc0[2].x + acc0[3].x);
  A0.y = (acc0[0].y + acc0[1].y) + (acc0[2].y + acc0[3].y);
  A0.z = (acc0[0].z + acc0[1].z) + (acc0[2].z + acc0[3].z);
  A0.w = (acc0[0].w + acc0[1].w) + (acc0[2].w + acc0[3].w);
  A1.x = (acc1[0].x + acc1[1].x) + (acc1[2].x + acc1[3].x);
  A1.y = (acc1[0].y + acc1[1].y) + (acc1[2].y + acc1[3].y);
  A1.z = (acc1[0].z + acc1[1].z) + (acc1[2].z + acc1[3].z);
  A1.w = (acc1[0].w + acc1[1].w) + (acc1[2].w + acc1[3].w);
  float D = (den[0] + den[1]) + (den[2] + den[3]);
  float inv = (e > s) ? 1.f / D : 0.f;
  A0.x *= inv; A0.y *= inv; A0.z *= inv; A0.w *= inv;
  A1.x *= inv; A1.y *= inv; A1.z *= inv; A1.w *= inv;
  if (RES) {
    float4 r0 = *(const float4*)(hres + (size_t)n * 128 + lane * 8);
    float4 r1 = *(const float4*)(hres + (size_t)n * 128 + lane * 8 + 4);
    A0.x += r0.x; A0.y += r0.y; A0.z += r0.z; A0.w += r0.w;
    A1.x += r1.x; A1.y += r1.y; A1.z += r1.z; A1.w += r1.w;
  }
  if (DOELU) {
    A0.x = (A0.x > 0.f) ? A0.x : expm1f(A0.x);
    A0.y = (A0.y > 0.f) ? A0.y : expm1f(A0.y);
    A0.z = (A0.z > 0.f) ? A0.z : expm1f(A0.z);
    A0.w = (A0.w > 0.f) ? A0.w : expm1f(A0.w);
    A1.x = (A1.x > 0.f) ? A1.x : expm1f(A1.x);
    A1.y = (A1.y > 0.f) ? A1.y : expm1f(A1.y);
    A1.z = (A1.z > 0.f) ? A1.z : expm1f(A1.z);
    A1.w = (A1.w > 0.f) ? A1.w : expm1f(A1.w);
  }
  *(float4*)(out + (size_t)n * 128 + lane * 8) = A0;
  *(float4*)(out + (size_t)n * 128 + lane * 8 + 4) = A1;
}

__global__ __launch_bounds__(256) void k_msg40v4(const __half* __restrict__ feat,
                                                 const float* __restrict__ el,
                                                 const float* __restrict__ er,
                                                 const int* __restrict__ row_off,
                                                 const int* __restrict__ esrc,
                                                 const float* __restrict__ res,
                                                 float* __restrict__ out, int nnodes) {
  int t = threadIdx.x;
  int n = blockIdx.x * 16 + (t >> 4);
  if (n >= nnodes) return;
  int lane = t & 15;
  int s = row_off[n], e = row_off[n + 1];
  float ern = er[n];
  float4 acc[2] = {};
  float den[2] = {0.f, 0.f};

  for (int c = s; c < e; c += 16) {
    int m = e - c; if (m > 16) m = 16;
    int sjv = 0;
    if (lane < m) sjv = esrc[c + lane];
    float selv = el[sjv];
    #pragma unroll
    for (int j = 0; j < 16; ++j) {
      if (j < m) {
        float ev = __shfl(selv, j, 16);
        float x = ev + ern;
        x = fmaxf(x, 0.2f * x);
        float wgt = __expf(x);
        int sj = __shfl(sjv, j, 16);
        den[j & 1] += wgt;
        if (lane < 10) {
          uint2 raw = *(const uint2*)(feat + (size_t)sj * 40 + lane * 4);
          const __half2* hp = (const __half2*)&raw;
          float2 f0 = __half22float2(hp[0]);
          float2 f1 = __half22float2(hp[1]);
          acc[j & 1].x += wgt * f0.x;
          acc[j & 1].y += wgt * f0.y;
          acc[j & 1].z += wgt * f1.x;
          acc[j & 1].w += wgt * f1.y;
        }
      }
    }
  }
  float D = den[0] + den[1];
  float inv = (e > s) ? 1.f / D : 0.f;
  if (lane < 10) {
    float4 r = *(const float4*)(res + (size_t)n * 40 + lane * 4);
    float4 A;
    A.x = (acc[0].x + acc[1].x) * inv + r.x;
    A.y = (acc[0].y + acc[1].y) * inv + r.y;
    A.z = (acc[0].z + acc[1].z) * inv + r.z;
    A.w = (acc[0].w + acc[1].w) * inv + r.w;
    *(float4*)(out + (size_t)n * 40 + lane * 4) = A;
  }
}

// ============================= launch =============================
extern "C" void kernel_launch(void* const* d_in, const int* in_sizes, int n_in,
                              void* d_out, int out_size, void* d_ws, size_t ws_size,
                              hipStream_t stream) {
  const float* features = (const float*)d_in[0];
  const float* W0 = (const float*)d_in[1];
  const float* al0 = (const float*)d_in[2];
  const float* ar0 = (const float*)d_in[3];
  const float* W1 = (const float*)d_in[4];
  const float* al1 = (const float*)d_in[5];
  const float* ar1 = (const float*)d_in[6];
  const float* W2 = (const float*)d_in[7];
  const float* al2 = (const float*)d_in[8];
  const float* ar2 = (const float*)d_in[9];
  const float* resW2 = (const float*)d_in[10];
  const int* src = (const int*)d_in[11];
  const int* dst = (const int*)d_in[12];
  float* out = (float*)d_out;

  const int N = NNODES;
  char* w = (char*)d_ws;
  auto alloc = [&](size_t bytes) {
    char* p = w;
    w += (bytes + 255) & ~(size_t)255;
    return p;
  };
  int* row_off = (int*)alloc((size_t)(N + 1) * 4);
  int* esrc = (int*)alloc((size_t)NEDGES * 4);
  unsigned* pack = (unsigned*)alloc((size_t)NEDGES * 4);
  unsigned* bucketed = (unsigned*)alloc((size_t)NEDGES * 4);
  int* hist2 = (int*)alloc(NBUCK * NSLICE * 4);
  int* off2 = (int*)alloc(NBUCK * NSLICE * 4);
  __half* feath = (__half*)alloc((size_t)N * 128 * 2);   // fp16 gather target
  float* res2 = (float*)alloc((size_t)N * 40 * 4);
  float* el = (float*)alloc((size_t)N * 4 * 4);
  float* er = (float*)alloc((size_t)N * 4 * 4);
  float* h1 = (float*)alloc((size_t)N * 128 * 4);
  float* h2 = (float*)alloc((size_t)N * 128 * 4);
  _Float16* Wt0 = (_Float16*)alloc(144 * 128 * 2);
  _Float16* Wt1 = (_Float16*)alloc(144 * 128 * 2);
  _Float16* Wt2 = (_Float16*)alloc(96 * 128 * 2);
  __half* feat2h = feath;  // layer-2 fp16 feat (N x 40) aliases feath

  // ---- weight prep (independent of CSR) ----
  k_prep<<<384, 128, 0, stream>>>(W0, al0, ar0, W1, al1, ar1, W2, resW2, al2, ar2,
                                  Wt0, Wt1, Wt2);

  // ---- CSR build via 2-level bucket sort ----
  hipMemsetAsync(hist2, 0, NBUCK * NSLICE * 4, stream);
  k_packhist<<<256, 256, 0, stream>>>(src, dst, pack, hist2);
  k_scan784<<<1, 1024, 0, stream>>>(hist2, off2);
  k_compact<<<NBUCK * NSLICE, 1024, 0, stream>>>(pack, off2, bucketed);
  k_sortbkt<<<NBUCK, 1024, 0, stream>>>(bucketed, off2, row_off, esrc);

  const int GB128 = (N + 127) / 128;  // 391
  const int GM = (N + 15) / 16;       // 3125

  // ---- layer 0 ----
  k_gemm_mfma<9, false><<<GB128, 512, 0, stream>>>(features, Wt0, feath, nullptr, el, er, N);
  k_msg128v4<false, true><<<GM, 256, 0, stream>>>(feath, el, er, row_off, esrc, nullptr, h1, N);

  // ---- layer 1 ----
  k_gemm_mfma<9, false><<<GB128, 512, 0, stream>>>(h1, Wt1, feath, nullptr, el, er, N);
  k_msg128v4<true, true><<<GM, 256, 0, stream>>>(feath, el, er, row_off, esrc, h1, h2, N);

  // ---- layer 2 (fused W2|resW2|el|er MFMA) ----
  k_gemm_mfma<6, true><<<GB128, 512, 0, stream>>>(h2, Wt2, feat2h, res2, el, er, N);
  k_msg40v4<<<GM, 256, 0, stream>>>(feat2h, el, er, row_off, esrc, res2, out, N);
}

// Round 7
// 202.804 us; speedup vs baseline: 1.2972x; 1.2972x over previous
//
#include <hip/hip_runtime.h>
#include <hip/hip_fp16.h>

#define NNODES 50000
#define NEDGES 800000
#define NBUCK 196       // dst>>8 buckets (256 nodes each)
#define NCHUNK 256
#define CHUNK 3125      // NEDGES / NCHUNK

typedef _Float16 f16x8 __attribute__((ext_vector_type(8)));
typedef float f32x4 __attribute__((ext_vector_type(4)));

// ============================= CSR build (radix partition) =================
// Edge packs into u32: (dst<<16)|src (both < 65536). bucket = dst>>8 = v>>24.

// Pass A: pack edges; per-chunk histogram (exclusive writes, no global atomics)
__global__ __launch_bounds__(256) void k_packhist(const int* __restrict__ src,
                                                  const int* __restrict__ dst,
                                                  unsigned* __restrict__ pack,
                                                  int* __restrict__ hist) {
  __shared__ int h[NBUCK];
  int t = threadIdx.x, c = blockIdx.x;
  for (int i = t; i < NBUCK; i += 256) h[i] = 0;
  __syncthreads();
  int beg = c * CHUNK;
  for (int q = t; q < CHUNK; q += 256) {
    int e = beg + q;
    unsigned d = (unsigned)dst[e], sv = (unsigned)src[e];
    pack[e] = (d << 16) | sv;
    atomicAdd(&h[d >> 8], 1);
  }
  __syncthreads();
  for (int i = t; i < NBUCK; i += 256) hist[i * NCHUNK + c] = h[i];
}

// Exclusive scan of hist[NBUCK*NCHUNK] (bucket-major) -> off. One block.
__global__ __launch_bounds__(1024) void k_scanall(const int* __restrict__ hist,
                                                  int* __restrict__ off) {
  __shared__ int sb[1024];
  int t = threadIdx.x;
  const int P = (NBUCK * NCHUNK) / 1024;  // 49
  int base = t * P;
  int s = 0;
  for (int i = 0; i < P; ++i) s += hist[base + i];
  sb[t] = s;
  __syncthreads();
  for (int o = 1; o < 1024; o <<= 1) {
    int x = (t >= o) ? sb[t - o] : 0;
    __syncthreads();
    sb[t] += x;
    __syncthreads();
  }
  int ex = sb[t] - s;
  for (int i = 0; i < P; ++i) {
    int v = hist[base + i];
    off[base + i] = ex;
    ex += v;
  }
}

// Pass B: single re-read of each chunk; append to bucket runs via LDS cursors.
__global__ __launch_bounds__(256) void k_partition(const unsigned* __restrict__ pack,
                                                   const int* __restrict__ off,
                                                   unsigned* __restrict__ bucketed) {
  __shared__ int cur[NBUCK];
  int t = threadIdx.x, c = blockIdx.x;
  for (int i = t; i < NBUCK; i += 256) cur[i] = off[i * NCHUNK + c];
  __syncthreads();
  int beg = c * CHUNK;
  for (int q = t; q < CHUNK; q += 256) {
    unsigned v = pack[beg + q];
    int pos = atomicAdd(&cur[v >> 24], 1);
    bucketed[pos] = v;
  }
}

// Per-bucket LDS counting sort (256-node range) -> row_off + esrc.
__global__ __launch_bounds__(256) void k_sortbkt(const unsigned* __restrict__ bucketed,
                                                 const int* __restrict__ off,
                                                 int* __restrict__ row_off,
                                                 int* __restrict__ esrc) {
  __shared__ int cnt[256];
  __shared__ int cur[256];
  int t = threadIdx.x, b = blockIdx.x;
  int base = off[b * NCHUNK];
  int endb = (b == NBUCK - 1) ? NEDGES : off[(b + 1) * NCHUNK];
  int ne = endb - base;
  cnt[t] = 0;
  __syncthreads();
  for (int i = t; i < ne; i += 256)
    atomicAdd(&cnt[(bucketed[base + i] >> 16) & 255], 1);
  __syncthreads();
  int orig = cnt[t];
  cur[t] = orig;
  __syncthreads();
  for (int o = 1; o < 256; o <<= 1) {
    int x = (t >= o) ? cur[t - o] : 0;
    __syncthreads();
    cur[t] += x;
    __syncthreads();
  }
  int excl = cur[t] - orig;
  int g = (b << 8) + t;
  if (g <= NNODES) row_off[g] = base + excl;
  cur[t] = excl;
  __syncthreads();
  for (int i = t; i < ne; i += 256) {
    unsigned v = bucketed[base + i];
    int pos = base + atomicAdd(&cur[(v >> 16) & 255], 1);
    esrc[pos] = (int)(v & 0xFFFFu);
  }
}

// ============================= weight prep =============================
// Wt0/Wt1: [144][128] fp16 = [W^T (128 rows) | W@al head cols (4) | W@ar (4) | zeros (8)]
// Wt2:     [96][128]  fp16 = [W2^T (40) | resW2^T (40) | W2@al2 | W2@ar2 | zeros (14)]
__global__ __launch_bounds__(128) void k_prep(const float* __restrict__ W0, const float* __restrict__ al0,
                                              const float* __restrict__ ar0,
                                              const float* __restrict__ W1, const float* __restrict__ al1,
                                              const float* __restrict__ ar1,
                                              const float* __restrict__ W2, const float* __restrict__ resW2,
                                              const float* __restrict__ al2, const float* __restrict__ ar2,
                                              _Float16* __restrict__ Wt0, _Float16* __restrict__ Wt1,
                                              _Float16* __restrict__ Wt2) {
  int b = blockIdx.x, k = threadIdx.x;
  if (b < 288) {
    const float* W = (b < 144) ? W0 : W1;
    const float* al = (b < 144) ? al0 : al1;
    const float* ar = (b < 144) ? ar0 : ar1;
    _Float16* Wt = (b < 144) ? Wt0 : Wt1;
    int c = (b < 144) ? b : b - 144;
    float v = 0.f;
    if (c < 128) {
      v = W[k * 128 + c];
    } else if (c < 136) {
      int h = c - 128;
      const float* av = (h < 4) ? al : ar;
      int hh = h & 3;
      float s = 0.f;
      for (int d = 0; d < 32; ++d) s += W[k * 128 + hh * 32 + d] * av[hh * 32 + d];
      v = s;
    }
    Wt[c * 128 + k] = (_Float16)v;
  } else {
    int c = b - 288;
    float v = 0.f;
    if (c < 40) {
      v = W2[k * 40 + c];
    } else if (c < 80) {
      v = resW2[k * 40 + (c - 40)];
    } else if (c == 80) {
      float s = 0.f;
      for (int d = 0; d < 40; ++d) s += W2[k * 40 + d] * al2[d];
      v = s;
    } else if (c == 81) {
      float s = 0.f;
      for (int d = 0; d < 40; ++d) s += W2[k * 40 + d] * ar2[d];
      v = s;
    }
    Wt2[c * 128 + k] = (_Float16)v;
  }
}

// ============================= MFMA GEMM =============================
template <int NCT, bool L2E>
__global__ __launch_bounds__(512) void k_gemm_mfma(const float* __restrict__ A,
                                                   const _Float16* __restrict__ Wtg,
                                                   __half* __restrict__ C,
                                                   float* __restrict__ resOut,
                                                   float* __restrict__ el,
                                                   float* __restrict__ er, int nrows) {
  __shared__ _Float16 Ah[128 * 136];
  __shared__ _Float16 Wl[NCT * 16 * 136];
  int t = threadIdx.x;
  int r0 = blockIdx.x * 128;

  for (int q = t; q < NCT * 16 * 16; q += 512) {
    int row = q >> 4, k8 = (q & 15) * 8;
    *(f16x8*)(&Wl[row * 136 + k8]) = *(const f16x8*)(Wtg + row * 128 + k8);
  }
  #pragma unroll
  for (int p = 0; p < 8; ++p) {
    int q = p * 512 + t;
    int r = q >> 5, k4 = (q & 31) * 4;
    float4 v = make_float4(0.f, 0.f, 0.f, 0.f);
    if (r0 + r < nrows) v = *(const float4*)(A + (size_t)(r0 + r) * 128 + k4);
    union { _Float16 h[4]; uint2 u; } pk;
    pk.h[0] = (_Float16)v.x; pk.h[1] = (_Float16)v.y;
    pk.h[2] = (_Float16)v.z; pk.h[3] = (_Float16)v.w;
    *(uint2*)(&Ah[r * 136 + k4]) = pk.u;
  }
  __syncthreads();

  int wave = t >> 6, l = t & 63;
  const _Float16* abase = &Ah[(wave * 16 + (l & 15)) * 136 + ((l >> 4) * 8)];
  const _Float16* bbase = &Wl[(l & 15) * 136 + ((l >> 4) * 8)];

  f32x4 acc[NCT] = {};
  #pragma unroll
  for (int ks = 0; ks < 4; ++ks) {
    f16x8 af = *(const f16x8*)(abase + ks * 32);
    #pragma unroll
    for (int nt = 0; nt < NCT; ++nt) {
      f16x8 bf = *(const f16x8*)(bbase + nt * 16 * 136 + ks * 32);
      acc[nt] = __builtin_amdgcn_mfma_f32_16x16x32_f16(af, bf, acc[nt], 0, 0, 0);
    }
  }

  int cc = l & 15;
  int rbase = r0 + wave * 16 + (l >> 4) * 4;
  #pragma unroll
  for (int r = 0; r < 4; ++r) {
    int row = rbase + r;
    if (row >= nrows) continue;
    if (!L2E) {
      #pragma unroll
      for (int nt = 0; nt < 8; ++nt)
        C[(size_t)row * 128 + nt * 16 + cc] = __float2half_rn(acc[nt][r]);
      float v = acc[8][r];
      if (cc < 4) el[row * 4 + cc] = v;
      else if (cc < 8) er[row * 4 + (cc - 4)] = v;
    } else {
      #pragma unroll
      for (int nt = 0; nt < 6; ++nt) {
        int col = nt * 16 + cc;
        float v = acc[nt][r];
        if (col < 40) C[(size_t)row * 40 + col] = __float2half_rn(v);
        else if (col < 80) resOut[(size_t)row * 40 + (col - 40)] = v;
        else if (col == 80) el[row] = v;
        else if (col == 81) er[row] = v;
      }
    }
  }
}

// ============================= helpers =============================
__device__ __forceinline__ void fma8h(float4& a0, float4& a1, float w, const uint4& r) {
  const __half2* hp = (const __half2*)&r;
  float2 f0 = __half22float2(hp[0]);
  float2 f1 = __half22float2(hp[1]);
  float2 f2 = __half22float2(hp[2]);
  float2 f3 = __half22float2(hp[3]);
  a0.x += w * f0.x; a0.y += w * f0.y; a0.z += w * f1.x; a0.w += w * f1.y;
  a1.x += w * f2.x; a1.y += w * f2.y; a1.z += w * f3.x; a1.w += w * f3.y;
}

// ============================= message passing (fp16 gather) =============
template <bool RES, bool DOELU>
__global__ __launch_bounds__(256) void k_msg128v4(const __half* __restrict__ feat,
                                                  const float* __restrict__ el,
                                                  const float* __restrict__ er,
                                                  const int* __restrict__ row_off,
                                                  const int* __restrict__ esrc,
                                                  const float* __restrict__ hres,
                                                  float* __restrict__ out, int nnodes) {
  int t = threadIdx.x;
  int n = blockIdx.x * 16 + (t >> 4);
  if (n >= nnodes) return;
  int lane = t & 15;          // cols lane*8 .. lane*8+7
  int h = lane >> 2;          // this lane's head
  int s = row_off[n], e = row_off[n + 1];
  float ern = er[n * 4 + h];
  float4 acc0[4] = {}, acc1[4] = {};
  float den[4] = {0.f, 0.f, 0.f, 0.f};

  for (int c = s; c < e; c += 16) {
    int m = e - c; if (m > 16) m = 16;
    int sjv = 0;
    if (lane < m) sjv = esrc[c + lane];
    int e0 = __shfl(sjv, (lane & 3), 16);
    int e1 = __shfl(sjv, (lane & 3) + 4, 16);
    int e2 = __shfl(sjv, (lane & 3) + 8, 16);
    int e3 = __shfl(sjv, (lane & 3) + 12, 16);
    float sel0 = el[e0 * 4 + h];
    float sel1 = el[e1 * 4 + h];
    float sel2 = el[e2 * 4 + h];
    float sel3 = el[e3 * 4 + h];

#define GAT_SUB(KK, SEL)                                                      \
    {                                                                         \
      int b = KK * 4;                                                         \
      if (b < m) {                                                            \
        int mm = m - b; if (mm > 4) mm = 4;                                   \
        _Pragma("unroll")                                                     \
        for (int j = 0; j < 4; ++j) {                                         \
          if (j < mm) {                                                       \
            float ev = __shfl(SEL, (lane & 12) | j, 16);                      \
            float x = ev + ern;                                               \
            x = fmaxf(x, 0.2f * x);                                           \
            float wgt = __expf(x);                                            \
            int sj = __shfl(sjv, b + j, 16);                                  \
            den[j] += wgt;                                                    \
            uint4 raw = *(const uint4*)(feat + (size_t)sj * 128 + lane * 8);  \
            fma8h(acc0[j], acc1[j], wgt, raw);                                \
          }                                                                   \
        }                                                                     \
      }                                                                       \
    }
    GAT_SUB(0, sel0)
    GAT_SUB(1, sel1)
    GAT_SUB(2, sel2)
    GAT_SUB(3, sel3)
#undef GAT_SUB
  }

  float4 A0, A1;
  A0.x = (acc0[0].x + acc0[1].x) + (acc0[2].x + acc0[3].x);
  A0.y = (acc0[0].y + acc0[1].y) + (acc0[2].y + acc0[3].y);
  A0.z = (acc0[0].z + acc0[1].z) + (acc0[2].z + acc0[3].z);
  A0.w = (acc0[0].w + acc0[1].w) + (acc0[2].w + acc0[3].w);
  A1.x = (acc1[0].x + acc1[1].x) + (acc1[2].x + acc1[3].x);
  A1.y = (acc1[0].y + acc1[1].y) + (acc1[2].y + acc1[3].y);
  A1.z = (acc1[0].z + acc1[1].z) + (acc1[2].z + acc1[3].z);
  A1.w = (acc1[0].w + acc1[1].w) + (acc1[2].w + acc1[3].w);
  float D = (den[0] + den[1]) + (den[2] + den[3]);
  float inv = (e > s) ? 1.f / D : 0.f;
  A0.x *= inv; A0.y *= inv; A0.z *= inv; A0.w *= inv;
  A1.x *= inv; A1.y *= inv; A1.z *= inv; A1.w *= inv;
  if (RES) {
    float4 r0 = *(const float4*)(hres + (size_t)n * 128 + lane * 8);
    float4 r1 = *(const float4*)(hres + (size_t)n * 128 + lane * 8 + 4);
    A0.x += r0.x; A0.y += r0.y; A0.z += r0.z; A0.w += r0.w;
    A1.x += r1.x; A1.y += r1.y; A1.z += r1.z; A1.w += r1.w;
  }
  if (DOELU) {
    A0.x = (A0.x > 0.f) ? A0.x : expm1f(A0.x);
    A0.y = (A0.y > 0.f) ? A0.y : expm1f(A0.y);
    A0.z = (A0.z > 0.f) ? A0.z : expm1f(A0.z);
    A0.w = (A0.w > 0.f) ? A0.w : expm1f(A0.w);
    A1.x = (A1.x > 0.f) ? A1.x : expm1f(A1.x);
    A1.y = (A1.y > 0.f) ? A1.y : expm1f(A1.y);
    A1.z = (A1.z > 0.f) ? A1.z : expm1f(A1.z);
    A1.w = (A1.w > 0.f) ? A1.w : expm1f(A1.w);
  }
  *(float4*)(out + (size_t)n * 128 + lane * 8) = A0;
  *(float4*)(out + (size_t)n * 128 + lane * 8 + 4) = A1;
}

__global__ __launch_bounds__(256) void k_msg40v4(const __half* __restrict__ feat,
                                                 const float* __restrict__ el,
                                                 const float* __restrict__ er,
                                                 const int* __restrict__ row_off,
                                                 const int* __restrict__ esrc,
                                                 const float* __restrict__ res,
                                                 float* __restrict__ out, int nnodes) {
  int t = threadIdx.x;
  int n = blockIdx.x * 16 + (t >> 4);
  if (n >= nnodes) return;
  int lane = t & 15;
  int s = row_off[n], e = row_off[n + 1];
  float ern = er[n];
  float4 acc[2] = {};
  float den[2] = {0.f, 0.f};

  for (int c = s; c < e; c += 16) {
    int m = e - c; if (m > 16) m = 16;
    int sjv = 0;
    if (lane < m) sjv = esrc[c + lane];
    float selv = el[sjv];
    #pragma unroll
    for (int j = 0; j < 16; ++j) {
      if (j < m) {
        float ev = __shfl(selv, j, 16);
        float x = ev + ern;
        x = fmaxf(x, 0.2f * x);
        float wgt = __expf(x);
        int sj = __shfl(sjv, j, 16);
        den[j & 1] += wgt;
        if (lane < 10) {
          uint2 raw = *(const uint2*)(feat + (size_t)sj * 40 + lane * 4);
          const __half2* hp = (const __half2*)&raw;
          float2 f0 = __half22float2(hp[0]);
          float2 f1 = __half22float2(hp[1]);
          acc[j & 1].x += wgt * f0.x;
          acc[j & 1].y += wgt * f0.y;
          acc[j & 1].z += wgt * f1.x;
          acc[j & 1].w += wgt * f1.y;
        }
      }
    }
  }
  float D = den[0] + den[1];
  float inv = (e > s) ? 1.f / D : 0.f;
  if (lane < 10) {
    float4 r = *(const float4*)(res + (size_t)n * 40 + lane * 4);
    float4 A;
    A.x = (acc[0].x + acc[1].x) * inv + r.x;
    A.y = (acc[0].y + acc[1].y) * inv + r.y;
    A.z = (acc[0].z + acc[1].z) * inv + r.z;
    A.w = (acc[0].w + acc[1].w) * inv + r.w;
    *(float4*)(out + (size_t)n * 40 + lane * 4) = A;
  }
}

// ============================= launch =============================
extern "C" void kernel_launch(void* const* d_in, const int* in_sizes, int n_in,
                              void* d_out, int out_size, void* d_ws, size_t ws_size,
                              hipStream_t stream) {
  const float* features = (const float*)d_in[0];
  const float* W0 = (const float*)d_in[1];
  const float* al0 = (const float*)d_in[2];
  const float* ar0 = (const float*)d_in[3];
  const float* W1 = (const float*)d_in[4];
  const float* al1 = (const float*)d_in[5];
  const float* ar1 = (const float*)d_in[6];
  const float* W2 = (const float*)d_in[7];
  const float* al2 = (const float*)d_in[8];
  const float* ar2 = (const float*)d_in[9];
  const float* resW2 = (const float*)d_in[10];
  const int* src = (const int*)d_in[11];
  const int* dst = (const int*)d_in[12];
  float* out = (float*)d_out;

  const int N = NNODES;
  char* w = (char*)d_ws;
  auto alloc = [&](size_t bytes) {
    char* p = w;
    w += (bytes + 255) & ~(size_t)255;
    return p;
  };
  int* row_off = (int*)alloc((size_t)(N + 1) * 4);
  int* esrc = (int*)alloc((size_t)NEDGES * 4);
  unsigned* pack = (unsigned*)alloc((size_t)NEDGES * 4);
  unsigned* bucketed = (unsigned*)alloc((size_t)NEDGES * 4);
  int* hist = (int*)alloc(NBUCK * NCHUNK * 4);
  int* off = (int*)alloc(NBUCK * NCHUNK * 4);
  __half* feath = (__half*)alloc((size_t)N * 128 * 2);   // fp16 gather target
  float* res2 = (float*)alloc((size_t)N * 40 * 4);
  float* el = (float*)alloc((size_t)N * 4 * 4);
  float* er = (float*)alloc((size_t)N * 4 * 4);
  float* h1 = (float*)alloc((size_t)N * 128 * 4);
  float* h2 = (float*)alloc((size_t)N * 128 * 4);
  _Float16* Wt0 = (_Float16*)alloc(144 * 128 * 2);
  _Float16* Wt1 = (_Float16*)alloc(144 * 128 * 2);
  _Float16* Wt2 = (_Float16*)alloc(96 * 128 * 2);
  __half* feat2h = feath;  // layer-2 fp16 feat (N x 40) aliases feath

  // ---- weight prep (independent of CSR) ----
  k_prep<<<384, 128, 0, stream>>>(W0, al0, ar0, W1, al1, ar1, W2, resW2, al2, ar2,
                                  Wt0, Wt1, Wt2);

  // ---- CSR build via radix partition ----
  k_packhist<<<NCHUNK, 256, 0, stream>>>(src, dst, pack, hist);
  k_scanall<<<1, 1024, 0, stream>>>(hist, off);
  k_partition<<<NCHUNK, 256, 0, stream>>>(pack, off, bucketed);
  k_sortbkt<<<NBUCK, 256, 0, stream>>>(bucketed, off, row_off, esrc);

  const int GB128 = (N + 127) / 128;  // 391
  const int GM = (N + 15) / 16;       // 3125

  // ---- layer 0 ----
  k_gemm_mfma<9, false><<<GB128, 512, 0, stream>>>(features, Wt0, feath, nullptr, el, er, N);
  k_msg128v4<false, true><<<GM, 256, 0, stream>>>(feath, el, er, row_off, esrc, nullptr, h1, N);

  // ---- layer 1 ----
  k_gemm_mfma<9, false><<<GB128, 512, 0, stream>>>(h1, Wt1, feath, nullptr, el, er, N);
  k_msg128v4<true, true><<<GM, 256, 0, stream>>>(feath, el, er, row_off, esrc, h1, h2, N);

  // ---- layer 2 (fused W2|resW2|el|er MFMA) ----
  k_gemm_mfma<6, true><<<GB128, 512, 0, stream>>>(h2, Wt2, feat2h, res2, el, er, N);
  k_msg40v4<<<GM, 256, 0, stream>>>(feat2h, el, er, row_off, esrc, res2, out, N);
}